// Round 9
// baseline (775.449 us; speedup 1.0000x reference)
//
#include <hip/hip_runtime.h>
#include <math.h>

constexpr int BB   = 4;
constexpr int CC   = 32;
constexpr int TT   = 131072;
constexpr int NFRM = 128;
constexpr int KK   = 1025;
constexpr int HOP  = 1024;
constexpr int SPF  = 512;
constexpr int SIGF = 256;
constexpr int NL   = 3;
constexpr int RST  = 2052;
constexpr int NBC  = BB*CC;           // 128
constexpr int NROWS = NBC*NFRM;       // 16384
constexpr int MAXNZ = 256;
constexpr int GRP  = 8;               // groups per bc
constexpr int FPG  = 16;              // frames per group

#define PD4(a) ((a) + ((a) >> 3))

__device__ __forceinline__ float4 f4add(float4 a, float4 b){return make_float4(a.x+b.x,a.y+b.y,a.z+b.z,a.w+b.w);}
__device__ __forceinline__ float4 f4sub(float4 a, float4 b){return make_float4(a.x-b.x,a.y-b.y,a.z-b.z,a.w-b.w);}
__device__ __forceinline__ float4 cmul4(float4 v, float c, float s){
  return make_float4(v.x*c - v.y*s, v.x*s + v.y*c, v.z*c - v.w*s, v.z*s + v.w*c);
}

template<int SGN>
__device__ __forceinline__ void dft4p(float4 v[4]) {
  float4 b0=f4add(v[0],v[2]), b1=f4sub(v[0],v[2]), b2=f4add(v[1],v[3]), b3=f4sub(v[1],v[3]);
  float4 ib3 = (SGN<0)? make_float4(b3.y,-b3.x,b3.w,-b3.z) : make_float4(-b3.y,b3.x,-b3.w,b3.z);
  v[0]=f4add(b0,b2); v[2]=f4sub(b0,b2);
  v[1]=f4add(b1,ib3); v[3]=f4sub(b1,ib3);
}

// Stockham radix-4 FFT-1024, 256 threads, two interleaved FFTs (.xy/.zw halves).
template<int SGN, bool FINAL_STORE>
__device__ __forceinline__ void stockham_pair(float4 v[4], float4* S4, int tid) {
  #pragma unroll
  for (int Ns=1; Ns<1024; Ns*=4) {
    if (Ns>1) {
      int k = tid & (Ns-1);
      float ang = (float)SGN * 6.28318530717958647692f * (float)k / (float)(4*Ns);
      float s1,c1; __sincosf(ang,&s1,&c1);
      float c2=c1*c1-s1*s1, s2=2.f*c1*s1;
      float c3=c2*c1-s2*s1, s3=c2*s1+s2*c1;
      v[1]=cmul4(v[1],c1,s1); v[2]=cmul4(v[2],c2,s2); v[3]=cmul4(v[3],c3,s3);
    }
    dft4p<SGN>(v);
    if (Ns<256 || FINAL_STORE) {
      int idxD = ((tid & ~(Ns-1))<<2) | (tid & (Ns-1));
      S4[PD4(idxD       )] = v[0];
      S4[PD4(idxD +   Ns)] = v[1];
      S4[PD4(idxD + 2*Ns)] = v[2];
      S4[PD4(idxD + 3*Ns)] = v[3];
      __syncthreads();
      if (Ns<256) {
        v[0]=S4[PD4(tid)]; v[1]=S4[PD4(tid+256)]; v[2]=S4[PD4(tid+512)]; v[3]=S4[PD4(tid+768)];
        __syncthreads();
      }
    }
  }
}

// ---------------- tables ----------------
__global__ void k_tables(const float* __restrict__ decay, float* __restrict__ ENVt,
                         float* __restrict__ HANN, float* __restrict__ PKt,
                         float* __restrict__ UPKt) {
  int gid = blockIdx.x*256 + threadIdx.x;
  if (gid < CC*SPF) {
    int c = gid >> 9, r = gid & 511;
    float d = decay[c];
    float env;
    if (r == 511) env = (d == 0.f) ? 1.f : 0.f;
    else          env = powf((float)(511-r)*(1.0f/511.0f), d);
    ENVt[gid] = env;
  }
  if (gid < 2048) HANN[gid] = 0.5f - 0.5f*cosf((float)gid*(float)(M_PI/1024.0));
  if (gid <= 1024) { float s,c; sincosf(-(float)M_PI*(float)gid*(1.0f/1024.0f),&s,&c); PKt[2*gid]=c; PKt[2*gid+1]=s; }
  if (gid <  1024) { float s,c; sincosf( (float)M_PI*(float)gid*(1.0f/1024.0f),&s,&c); UPKt[2*gid]=c; UPKt[2*gid+1]=s; }
}

// ---------------- sparse transfers: compact then expand ----------------
__global__ void __launch_bounds__(64) k_nnz(const float* __restrict__ tr,
    int* __restrict__ NZI, float* __restrict__ NZV, int* __restrict__ NZC) {
  int lc = blockIdx.x;
  int lane = threadIdx.x;
  const float* trow = tr + (size_t)lc*KK;
  int base = 0;
  for (int start = 0; start < KK; start += 64) {
    int kp = start + lane;
    float v = (kp < KK) ? trow[kp] : 0.f;
    unsigned long long m = __ballot(v != 0.f);
    int pos = base + __popcll(m & ((1ull<<lane)-1ull));
    if (v != 0.f && pos < MAXNZ) { NZI[lc*MAXNZ+pos] = kp; NZV[lc*MAXNZ+pos] = v; }
    base += __popcll(m);
  }
  if (lane == 0) NZC[lc] = (base < MAXNZ) ? base : MAXNZ;
}

__global__ void __launch_bounds__(256) k_tmat2(const int* __restrict__ NZI,
    const float* __restrict__ NZV, const int* __restrict__ NZC,
    const float* __restrict__ fb, float* __restrict__ TM) {
  int gid = blockIdx.x*256 + threadIdx.x;
  if (gid >= NL*CC*KK) return;
  int k = gid % KK, lc = gid / KK;
  int n = NZC[lc];
  const int*   zi = NZI + lc*MAXNZ;
  const float* zv = NZV + lc*MAXNZ;
  float acc = 0.f;
  for (int i = 0; i < n; ++i)
    acc = fmaf(zv[i], fb[(size_t)zi[i]*KK + k], acc);
  TM[gid] = acc;
}

// ---------------- per-layer identity check on mixer matrices ----------------
__global__ void k_ident(const float* __restrict__ mats, int* __restrict__ FLG) {
  int l = blockIdx.x;
  const float* M = mats + (size_t)l*CC*CC;
  __shared__ int ok;
  if (threadIdx.x == 0) ok = 1;
  __syncthreads();
  for (int i = threadIdx.x; i < CC*CC; i += 256) {
    float ex = ((i>>5) == (i&31)) ? 1.f : 0.f;
    if (M[i] != ex) ok = 0;
  }
  __syncthreads();
  if (threadIdx.x == 0) FLG[l] = ok;
}

// ---------------- fused upsample+envelope+noise + layer-0 mix + out init + sig copy ------
__global__ void __launch_bounds__(256) k_us_init(const float* __restrict__ sig,
    const float* __restrict__ noise, const float* __restrict__ mixer,
    const float* __restrict__ M0, const float* __restrict__ ENVt,
    float* __restrict__ X, float* __restrict__ out) {
  __shared__ float sM[CC*CC];
  int tid = threadIdx.x;
  for (int i = tid; i < CC*CC; i += 256) sM[i] = M0[i];
  __syncthreads();
  int gid = blockIdx.x*256 + tid;
  int b = gid >> 17, t = gid & (TT-1);
  int q = t >> 9, r = t & 511;
  float nz = noise[t];
  float u[CC]; float s = 0.f;
  #pragma unroll
  for (int c = 0; c < CC; ++c) { u[c] = sig[(b*CC+c)*SIGF + q] * ENVt[c*SPF + r]; s += u[c]; }
  float m0=mixer[0],m1=mixer[1],m2=mixer[2],m3=mixer[3];
  float mx=fmaxf(fmaxf(m0,m1),fmaxf(m2,m3));
  float e0=__expf(m0-mx),e1=__expf(m1-mx),e2=__expf(m2-mx),e3=__expf(m3-mx);
  float w0=e0/(e0+e1+e2+e3);
  out[gid] = w0 * nz * s;
  #pragma unroll
  for (int d = 0; d < CC; ++d) {
    float acc = 0.f;
    #pragma unroll
    for (int c = 0; c < CC; ++c) acc = fmaf(u[c], sM[c*CC+d], acc);
    X[(size_t)(b*CC+d)*TT + t] = nz * acc;
  }
  if (gid < BB*CC*SIGF) out[BB*TT + gid] = sig[gid];
}

// ---------------- conditional in-place channel mix (no-op when identity) -----------------
__global__ void __launch_bounds__(256) k_mix_cond(float* __restrict__ X,
    const float* __restrict__ M, const int* __restrict__ FLG, int layer) {
  if (FLG[layer]) return;
  __shared__ float sM[CC*CC];
  int tid = threadIdx.x;
  for (int i = tid; i < CC*CC; i += 256) sM[i] = M[i];
  __syncthreads();
  int gid = blockIdx.x*256 + tid;
  int b = gid >> 17, t = gid & (TT-1);
  float* xp = X + (size_t)b*CC*TT + t;
  float xv[CC];
  #pragma unroll
  for (int c = 0; c < CC; ++c) xv[c] = xp[(size_t)c*TT];
  for (int d = 0; d < CC; ++d) {
    float acc = 0.f;
    #pragma unroll
    for (int c = 0; c < CC; ++c) acc = fmaf(xv[c], sM[c*CC+d], acc);
    xp[(size_t)d*TT] = acc;
  }
}

// ---------------- fused forward FFT + chunk-local scan (FPG=16, 8 pair rounds) ----------
__global__ void __launch_bounds__(256) k_fwd_scan(const float* __restrict__ X,
    float* __restrict__ SPEC, float* __restrict__ EB, const float* __restrict__ TM,
    const float* __restrict__ HANN, const float* __restrict__ PKt) {
  __shared__ float4 S4[1152];
  int tid = threadIdx.x;
  int blk = blockIdx.x;                 // bc*GRP + g
  int g = blk & (GRP-1), bc = blk >> 3;
  int c = bc & (CC-1);
  const float* xr = X + (size_t)bc*TT;
  float Tv[5]; float2 cr[5];
  #pragma unroll
  for (int j = 0; j < 5; ++j) {
    int k = tid + 256*j;
    Tv[j] = (k <= 1024) ? TM[c*KK + k] : 0.f;
    cr[j] = make_float2(0.f, 0.f);
  }
  for (int p = 0; p < FPG/2; ++p) {
    int f0 = g*FPG + 2*p;
    int s0 = f0*HOP;
    float4 v[4];
    #pragma unroll
    for (int r = 0; r < 4; ++r) {
      int n = tid + 256*r;
      float2 h = *(const float2*)(HANN + 2*n);
      float2 a = *(const float2*)(xr + s0 + 2*n);
      int sb = s0 + HOP + 2*n;
      float2 bb = (sb < TT) ? *(const float2*)(xr + sb) : make_float2(0.f,0.f);
      v[r] = make_float4(a.x*h.x, a.y*h.y, bb.x*h.x, bb.y*h.y);
    }
    stockham_pair<-1, true>(v, S4, tid);
    float* row0 = SPEC + (size_t)(bc*NFRM + f0)*RST;
    float* row1 = row0 + RST;
    #pragma unroll
    for (int j = 0; j < 5; ++j) {
      int k = tid + 256*j;
      if (k <= 1024) {
        float4 Zk = S4[PD4(k & 1023)];
        float4 Zm = S4[PD4((1024-k) & 1023)];
        float2 pk = *(const float2*)(PKt + 2*k);
        float zex = 0.5f*(Zk.x+Zm.x), zey = 0.5f*(Zk.y-Zm.y);
        float zox = 0.5f*(Zk.y+Zm.y), zoy = -0.5f*(Zk.x-Zm.x);
        float sax = zex + pk.x*zox - pk.y*zoy;
        float say = zey + pk.x*zoy + pk.y*zox;
        zex = 0.5f*(Zk.z+Zm.z); zey = 0.5f*(Zk.w-Zm.w);
        zox = 0.5f*(Zk.w+Zm.w); zoy = -0.5f*(Zk.z-Zm.z);
        float sbx = zex + pk.x*zox - pk.y*zoy;
        float sby = zey + pk.x*zoy + pk.y*zox;
        cr[j].x = (sax + cr[j].x)*Tv[j];
        cr[j].y = (say + cr[j].y)*Tv[j];
        *(float2*)(row0 + 2*k) = cr[j];
        cr[j].x = (sbx + cr[j].x)*Tv[j];
        cr[j].y = (sby + cr[j].y)*Tv[j];
        *(float2*)(row1 + 2*k) = cr[j];
      }
    }
    __syncthreads();
  }
  float* er = EB + (size_t)blk*RST;     // group-end local carry E_g
  #pragma unroll
  for (int j = 0; j < 5; ++j) {
    int k = tid + 256*j;
    if (k <= 1024) *(float2*)(er + 2*k) = cr[j];
  }
}

// ---------------- carry propagation across groups (in place: E -> carry-IN) -------------
__global__ void __launch_bounds__(256) k_carry(float* __restrict__ EB, const float* __restrict__ TM) {
  int gid = blockIdx.x*256 + threadIdx.x;
  if (gid >= NBC*KK) return;
  int bc = gid / KK, k = gid - bc*KK;
  int c = bc & (CC-1);
  float T = TM[c*KK + k];
  float t2 = T*T, t4 = t2*t2, t8 = t4*t4, T16 = t8*t8;
  float2 cc = make_float2(0.f, 0.f);
  for (int g = 0; g < GRP; ++g) {
    float* p = EB + (size_t)(bc*GRP + g)*RST + 2*k;
    float2 e = *(float2*)p;
    *(float2*)p = cc;                   // carry-in C_{g-1} for group g
    cc.x = e.x + T16*cc.x;              // C_g = E_g + T^16 C_{g-1}
    cc.y = e.y + T16*cc.y;
  }
}

// ---------------- fused carry-apply + irfft + hann + OLA + tanh -> X (+ atomic out) ------
__global__ void __launch_bounds__(256) k_inv_ola(const float* __restrict__ SPEC,
    const float* __restrict__ EB, const float* __restrict__ TM,
    const float* __restrict__ HANN, const float* __restrict__ UPKt,
    const float* __restrict__ gains, const float* __restrict__ mixer, int layer,
    int writeX, float* __restrict__ X, float* __restrict__ out) {
  __shared__ float4 S4[1152];
  int tid = threadIdx.x;
  int blk = blockIdx.x;
  int g = blk & (GRP-1), bc = blk >> 3;
  int c = bc & (CC-1);
  int b = bc / CC;
  int fb = g*FPG;
  float sg = gains[c];
  float m0=mixer[0],m1=mixer[1],m2=mixer[2],m3=mixer[3];
  float mx=fmaxf(fmaxf(m0,m1),fmaxf(m2,m3));
  float e0=__expf(m0-mx),e1=__expf(m1-mx),e2=__expf(m2-mx),e3=__expf(m3-mx);
  float ww = ((layer==0)?e1:(layer==1)?e2:e3) / (e0+e1+e2+e3);
  const float* ec = EB + (size_t)blk*RST;     // carry-in spectrum C_{g-1}
  // decayed carry: dN/dM start at C; multiply by T once per frame step
  float Tn[4], Tm[4]; float2 dN[4], dM[4];
  #pragma unroll
  for (int r = 0; r < 4; ++r) {
    int n = tid + 256*r, m = 1024 - n;
    Tn[r] = TM[c*KK + n]; Tm[r] = TM[c*KK + m];
    dN[r] = *(const float2*)(ec + 2*n);
    dM[r] = *(const float2*)(ec + 2*m);
  }
  float2 pr0 = make_float2(0.f,0.f), pr1 = make_float2(0.f,0.f); // prev frame 2nd half
  float* xw = X + (size_t)bc*TT;
  float* ob = out + (size_t)b*TT;
  const float sc = 1.0f/1024.0f;
  for (int rnd = 0; rnd < FPG/2 + 1; ++rnd) {     // 9 rounds
    float4 v[4];
    #pragma unroll
    for (int r = 0; r < 4; ++r) {
      int n = tid + 256*r, m = 1024 - n;
      float2 An, Am, Bn, Bm;
      if (rnd == 0) { An = dN[r]; Am = dM[r]; }   // prev frame output = carry itself
      else {
        const float* rowA = SPEC + (size_t)(bc*NFRM + fb + 2*rnd - 1)*RST;
        float2 a = *(const float2*)(rowA + 2*n);
        float2 bv = *(const float2*)(rowA + 2*m);
        dN[r].x *= Tn[r]; dN[r].y *= Tn[r];
        dM[r].x *= Tm[r]; dM[r].y *= Tm[r];
        An = make_float2(a.x + dN[r].x, a.y + dN[r].y);
        Am = make_float2(bv.x + dM[r].x, bv.y + dM[r].y);
      }
      if (rnd < FPG/2) {
        const float* rowB = SPEC + (size_t)(bc*NFRM + fb + 2*rnd)*RST;
        float2 a = *(const float2*)(rowB + 2*n);
        float2 bv = *(const float2*)(rowB + 2*m);
        dN[r].x *= Tn[r]; dN[r].y *= Tn[r];
        dM[r].x *= Tm[r]; dM[r].y *= Tm[r];
        Bn = make_float2(a.x + dN[r].x, a.y + dN[r].y);
        Bm = make_float2(bv.x + dM[r].x, bv.y + dM[r].y);
      } else { Bn = make_float2(0.f,0.f); Bm = make_float2(0.f,0.f); }
      float2 u = *(const float2*)(UPKt + 2*n);
      float zex = 0.5f*(An.x+Am.x), zey = 0.5f*(An.y-Am.y);
      float dx  = 0.5f*(An.x-Am.x), dy  = 0.5f*(An.y+Am.y);
      float zox = u.x*dx - u.y*dy, zoy = u.x*dy + u.y*dx;
      v[r].x = zex - zoy; v[r].y = zey + zox;
      zex = 0.5f*(Bn.x+Bm.x); zey = 0.5f*(Bn.y-Bm.y);
      dx  = 0.5f*(Bn.x-Bm.x); dy  = 0.5f*(Bn.y+Bm.y);
      zox = u.x*dx - u.y*dy; zoy = u.x*dy + u.y*dx;
      v[r].z = zex - zoy; v[r].w = zey + zox;
    }
    stockham_pair<1, false>(v, S4, tid);
    #pragma unroll
    for (int r = 0; r < 4; ++r) {        // hann + 1/1024 scale -> windowed frames
      int n = tid + 256*r;
      float2 h = *(const float2*)(HANN + 2*n);
      v[r].x *= sc*h.x; v[r].y *= sc*h.y;
      v[r].z *= sc*h.x; v[r].w *= sc*h.y;
    }
    if (rnd >= 1) {                      // emit frame fb+2rnd-1 (slot A)
      int tbase = (fb + 2*rnd - 1)*HOP;
      float2 o0 = make_float2(tanhf(sg*(v[0].x + pr0.x)), tanhf(sg*(v[0].y + pr0.y)));
      float2 o1 = make_float2(tanhf(sg*(v[1].x + pr1.x)), tanhf(sg*(v[1].y + pr1.y)));
      if (writeX) {
        *(float2*)(xw + tbase + 2*tid)        = o0;
        *(float2*)(xw + tbase + 2*(tid+256))  = o1;
      }
      atomicAdd(ob + tbase + 2*tid,       ww*o0.x);
      atomicAdd(ob + tbase + 2*tid + 1,   ww*o0.y);
      atomicAdd(ob + tbase + 2*(tid+256),     ww*o1.x);
      atomicAdd(ob + tbase + 2*(tid+256) + 1, ww*o1.y);
    }
    if (rnd < FPG/2) {                   // emit frame fb+2rnd (slot B)
      int tbase = (fb + 2*rnd)*HOP;
      float2 o0 = make_float2(tanhf(sg*(v[0].z + v[2].x)), tanhf(sg*(v[0].w + v[2].y)));
      float2 o1 = make_float2(tanhf(sg*(v[1].z + v[3].x)), tanhf(sg*(v[1].w + v[3].y)));
      if (writeX) {
        *(float2*)(xw + tbase + 2*tid)        = o0;
        *(float2*)(xw + tbase + 2*(tid+256))  = o1;
      }
      atomicAdd(ob + tbase + 2*tid,       ww*o0.x);
      atomicAdd(ob + tbase + 2*tid + 1,   ww*o0.y);
      atomicAdd(ob + tbase + 2*(tid+256),     ww*o1.x);
      atomicAdd(ob + tbase + 2*(tid+256) + 1, ww*o1.y);
      pr0 = make_float2(v[2].z, v[2].w);
      pr1 = make_float2(v[3].z, v[3].w);
    }
  }
}

extern "C" void kernel_launch(void* const* d_in, const int* in_sizes, int n_in,
                              void* d_out, int out_size, void* d_ws, size_t ws_size,
                              hipStream_t stream) {
  const float* sig        = (const float*)d_in[0];
  const float* noise      = (const float*)d_in[1];
  const float* decay      = (const float*)d_in[2];
  const float* mixer      = (const float*)d_in[3];
  const float* transfers  = (const float*)d_in[4];
  const float* mixer_mats = (const float*)d_in[5];
  const float* gains      = (const float*)d_in[6];
  const float* fb         = (const float*)d_in[7];
  float* out = (float*)d_out;
  float* ws  = (float*)d_ws;

  // ws floats: X 16.78M | SPEC 33.62M | EB 2.10M | TM 98K | tables | NZ* | FLG (~211 MB)
  float* X    = ws;
  float* SPEC = X + (size_t)16777216;
  float* EB   = SPEC + (size_t)NROWS*RST;
  float* TM   = EB + (size_t)NBC*GRP*RST;
  float* ENVt = TM + (size_t)NL*CC*KK;
  float* HANN = ENVt + CC*SPF;
  float* PKt  = HANN + 2048;
  float* UPKt = PKt + 2050;
  float* NZVf = UPKt + 2048;
  int*   NZI  = (int*)(NZVf + NL*CC*MAXNZ);
  int*   NZC  = NZI + NL*CC*MAXNZ;
  int*   FLG  = NZC + NL*CC;

  k_tables<<<64, 256, 0, stream>>>(decay, ENVt, HANN, PKt, UPKt);
  k_nnz<<<NL*CC, 64, 0, stream>>>(transfers, NZI, NZVf, NZC);
  k_tmat2<<<(NL*CC*KK + 255)/256, 256, 0, stream>>>(NZI, NZVf, NZC, fb, TM);
  k_ident<<<NL, 256, 0, stream>>>(mixer_mats, FLG);
  k_us_init<<<BB*TT/256, 256, 0, stream>>>(sig, noise, mixer, mixer_mats, ENVt, X, out);

  for (int l = 0; l < NL; ++l) {
    const float* TMl = TM + (size_t)l*CC*KK;
    if (l > 0)
      k_mix_cond<<<BB*TT/256, 256, 0, stream>>>(X, mixer_mats + (size_t)l*CC*CC, FLG, l);
    k_fwd_scan<<<NBC*GRP, 256, 0, stream>>>(X, SPEC, EB, TMl, HANN, PKt);
    k_carry<<<(NBC*KK + 255)/256, 256, 0, stream>>>(EB, TMl);
    k_inv_ola<<<NBC*GRP, 256, 0, stream>>>(SPEC, EB, TMl, HANN, UPKt,
                                           gains + (size_t)l*CC, mixer, l,
                                           (l < NL-1) ? 1 : 0, X, out);
  }
}

// Round 10
// 532.542 us; speedup vs baseline: 1.4561x; 1.4561x over previous
//
#include <hip/hip_runtime.h>
#include <math.h>

constexpr int BB   = 4;
constexpr int CC   = 32;
constexpr int TT   = 131072;
constexpr int NFRM = 128;
constexpr int KK   = 1025;
constexpr int HOP  = 1024;
constexpr int SPF  = 512;
constexpr int SIGF = 256;
constexpr int NL   = 3;
constexpr int RST  = 2052;
constexpr int NBC  = BB*CC;           // 128
constexpr int NROWS = NBC*NFRM;       // 16384
constexpr int MAXNZ = 256;
constexpr int GRP  = 8;               // groups per bc  (FPG=16 was best: R7=532us; FPG=8 regressed R8)
constexpr int FPG  = 16;              // frames per group

#define PD4(a) ((a) + ((a) >> 3))

__device__ __forceinline__ float4 f4add(float4 a, float4 b){return make_float4(a.x+b.x,a.y+b.y,a.z+b.z,a.w+b.w);}
__device__ __forceinline__ float4 f4sub(float4 a, float4 b){return make_float4(a.x-b.x,a.y-b.y,a.z-b.z,a.w-b.w);}
__device__ __forceinline__ float4 cmul4(float4 v, float c, float s){
  return make_float4(v.x*c - v.y*s, v.x*s + v.y*c, v.z*c - v.w*s, v.z*s + v.w*c);
}

template<int SGN>
__device__ __forceinline__ void dft4p(float4 v[4]) {
  float4 b0=f4add(v[0],v[2]), b1=f4sub(v[0],v[2]), b2=f4add(v[1],v[3]), b3=f4sub(v[1],v[3]);
  float4 ib3 = (SGN<0)? make_float4(b3.y,-b3.x,b3.w,-b3.z) : make_float4(-b3.y,b3.x,-b3.w,b3.z);
  v[0]=f4add(b0,b2); v[2]=f4sub(b0,b2);
  v[1]=f4add(b1,ib3); v[3]=f4sub(b1,ib3);
}

// Stockham radix-4 FFT-1024, 256 threads, two interleaved FFTs (.xy/.zw halves).
template<int SGN, bool FINAL_STORE>
__device__ __forceinline__ void stockham_pair(float4 v[4], float4* S4, int tid) {
  #pragma unroll
  for (int Ns=1; Ns<1024; Ns*=4) {
    if (Ns>1) {
      int k = tid & (Ns-1);
      float ang = (float)SGN * 6.28318530717958647692f * (float)k / (float)(4*Ns);
      float s1,c1; __sincosf(ang,&s1,&c1);
      float c2=c1*c1-s1*s1, s2=2.f*c1*s1;
      float c3=c2*c1-s2*s1, s3=c2*s1+s2*c1;
      v[1]=cmul4(v[1],c1,s1); v[2]=cmul4(v[2],c2,s2); v[3]=cmul4(v[3],c3,s3);
    }
    dft4p<SGN>(v);
    if (Ns<256 || FINAL_STORE) {
      int idxD = ((tid & ~(Ns-1))<<2) | (tid & (Ns-1));
      S4[PD4(idxD       )] = v[0];
      S4[PD4(idxD +   Ns)] = v[1];
      S4[PD4(idxD + 2*Ns)] = v[2];
      S4[PD4(idxD + 3*Ns)] = v[3];
      __syncthreads();
      if (Ns<256) {
        v[0]=S4[PD4(tid)]; v[1]=S4[PD4(tid+256)]; v[2]=S4[PD4(tid+512)]; v[3]=S4[PD4(tid+768)];
        __syncthreads();
      }
    }
  }
}

// ---------------- tables ----------------
__global__ void k_tables(const float* __restrict__ decay, float* __restrict__ ENVt,
                         float* __restrict__ HANN, float* __restrict__ PKt,
                         float* __restrict__ UPKt) {
  int gid = blockIdx.x*256 + threadIdx.x;
  if (gid < CC*SPF) {
    int c = gid >> 9, r = gid & 511;
    float d = decay[c];
    float env;
    if (r == 511) env = (d == 0.f) ? 1.f : 0.f;
    else          env = powf((float)(511-r)*(1.0f/511.0f), d);
    ENVt[gid] = env;
  }
  if (gid < 2048) HANN[gid] = 0.5f - 0.5f*cosf((float)gid*(float)(M_PI/1024.0));
  if (gid <= 1024) { float s,c; sincosf(-(float)M_PI*(float)gid*(1.0f/1024.0f),&s,&c); PKt[2*gid]=c; PKt[2*gid+1]=s; }
  if (gid <  1024) { float s,c; sincosf( (float)M_PI*(float)gid*(1.0f/1024.0f),&s,&c); UPKt[2*gid]=c; UPKt[2*gid+1]=s; }
}

// ---------------- sparse transfers: compact then expand ----------------
__global__ void __launch_bounds__(64) k_nnz(const float* __restrict__ tr,
    int* __restrict__ NZI, float* __restrict__ NZV, int* __restrict__ NZC) {
  int lc = blockIdx.x;
  int lane = threadIdx.x;
  const float* trow = tr + (size_t)lc*KK;
  int base = 0;
  for (int start = 0; start < KK; start += 64) {
    int kp = start + lane;
    float v = (kp < KK) ? trow[kp] : 0.f;
    unsigned long long m = __ballot(v != 0.f);
    int pos = base + __popcll(m & ((1ull<<lane)-1ull));
    if (v != 0.f && pos < MAXNZ) { NZI[lc*MAXNZ+pos] = kp; NZV[lc*MAXNZ+pos] = v; }
    base += __popcll(m);
  }
  if (lane == 0) NZC[lc] = (base < MAXNZ) ? base : MAXNZ;
}

__global__ void __launch_bounds__(256) k_tmat2(const int* __restrict__ NZI,
    const float* __restrict__ NZV, const int* __restrict__ NZC,
    const float* __restrict__ fb, float* __restrict__ TM) {
  int gid = blockIdx.x*256 + threadIdx.x;
  if (gid >= NL*CC*KK) return;
  int k = gid % KK, lc = gid / KK;
  int n = NZC[lc];
  const int*   zi = NZI + lc*MAXNZ;
  const float* zv = NZV + lc*MAXNZ;
  float acc = 0.f;
  for (int i = 0; i < n; ++i)
    acc = fmaf(zv[i], fb[(size_t)zi[i]*KK + k], acc);
  TM[gid] = acc;
}

// ---------------- per-layer identity check on mixer matrices ----------------
__global__ void k_ident(const float* __restrict__ mats, int* __restrict__ FLG) {
  int l = blockIdx.x;
  const float* M = mats + (size_t)l*CC*CC;
  __shared__ int ok;
  if (threadIdx.x == 0) ok = 1;
  __syncthreads();
  for (int i = threadIdx.x; i < CC*CC; i += 256) {
    float ex = ((i>>5) == (i&31)) ? 1.f : 0.f;
    if (M[i] != ex) ok = 0;
  }
  __syncthreads();
  if (threadIdx.x == 0) FLG[l] = ok;
}

// ---------------- fused upsample+envelope+noise + layer-0 mix + out init + sig copy ------
__global__ void __launch_bounds__(256) k_us_init(const float* __restrict__ sig,
    const float* __restrict__ noise, const float* __restrict__ mixer,
    const float* __restrict__ M0, const float* __restrict__ ENVt,
    float* __restrict__ X, float* __restrict__ out) {
  __shared__ float sM[CC*CC];
  int tid = threadIdx.x;
  for (int i = tid; i < CC*CC; i += 256) sM[i] = M0[i];
  __syncthreads();
  int gid = blockIdx.x*256 + tid;
  int b = gid >> 17, t = gid & (TT-1);
  int q = t >> 9, r = t & 511;
  float nz = noise[t];
  float u[CC]; float s = 0.f;
  #pragma unroll
  for (int c = 0; c < CC; ++c) { u[c] = sig[(b*CC+c)*SIGF + q] * ENVt[c*SPF + r]; s += u[c]; }
  float m0=mixer[0],m1=mixer[1],m2=mixer[2],m3=mixer[3];
  float mx=fmaxf(fmaxf(m0,m1),fmaxf(m2,m3));
  float e0=__expf(m0-mx),e1=__expf(m1-mx),e2=__expf(m2-mx),e3=__expf(m3-mx);
  float w0=e0/(e0+e1+e2+e3);
  out[gid] = w0 * nz * s;
  #pragma unroll
  for (int d = 0; d < CC; ++d) {
    float acc = 0.f;
    #pragma unroll
    for (int c = 0; c < CC; ++c) acc = fmaf(u[c], sM[c*CC+d], acc);
    X[(size_t)(b*CC+d)*TT + t] = nz * acc;
  }
  if (gid < BB*CC*SIGF) out[BB*TT + gid] = sig[gid];
}

// ---------------- conditional in-place channel mix (no-op when identity) -----------------
__global__ void __launch_bounds__(256) k_mix_cond(float* __restrict__ X,
    const float* __restrict__ M, const int* __restrict__ FLG, int layer) {
  if (FLG[layer]) return;
  __shared__ float sM[CC*CC];
  int tid = threadIdx.x;
  for (int i = tid; i < CC*CC; i += 256) sM[i] = M[i];
  __syncthreads();
  int gid = blockIdx.x*256 + tid;
  int b = gid >> 17, t = gid & (TT-1);
  float* xp = X + (size_t)b*CC*TT + t;
  float xv[CC];
  #pragma unroll
  for (int c = 0; c < CC; ++c) xv[c] = xp[(size_t)c*TT];
  for (int d = 0; d < CC; ++d) {
    float acc = 0.f;
    #pragma unroll
    for (int c = 0; c < CC; ++c) acc = fmaf(xv[c], sM[c*CC+d], acc);
    xp[(size_t)d*TT] = acc;
  }
}

// ---------------- fused forward FFT + chunk-local scan, input software-pipelined --------
__global__ void __launch_bounds__(256) k_fwd_scan(const float* __restrict__ X,
    float* __restrict__ SPEC, float* __restrict__ EB, const float* __restrict__ TM,
    const float* __restrict__ HANN, const float* __restrict__ PKt) {
  __shared__ float4 S4[1152];
  int tid = threadIdx.x;
  int blk = blockIdx.x;                 // bc*GRP + g
  int g = blk & (GRP-1), bc = blk >> 3;
  int c = bc & (CC-1);
  const float* xr = X + (size_t)bc*TT;
  float Tv[5]; float2 cr[5];
  #pragma unroll
  for (int j = 0; j < 5; ++j) {
    int k = tid + 256*j;
    Tv[j] = (k <= 1024) ? TM[c*KK + k] : 0.f;
    cr[j] = make_float2(0.f, 0.f);
  }
  // preload pair 0 input
  float2 inA[4], inB[4];
  {
    int s0 = g*FPG*HOP;
    #pragma unroll
    for (int r = 0; r < 4; ++r) {
      int n = tid + 256*r;
      inA[r] = *(const float2*)(xr + s0 + 2*n);
      int sb = s0 + HOP + 2*n;
      inB[r] = (sb < TT) ? *(const float2*)(xr + sb) : make_float2(0.f,0.f);
    }
  }
  for (int p = 0; p < FPG/2; ++p) {
    int f0 = g*FPG + 2*p;
    float4 v[4];
    #pragma unroll
    for (int r = 0; r < 4; ++r) {
      int n = tid + 256*r;
      float2 h = *(const float2*)(HANN + 2*n);
      v[r] = make_float4(inA[r].x*h.x, inA[r].y*h.y, inB[r].x*h.x, inB[r].y*h.y);
    }
    if (p < FPG/2 - 1) {                // prefetch pair p+1 input before FFT (latency hidden)
      int s0 = (f0 + 2)*HOP;
      #pragma unroll
      for (int r = 0; r < 4; ++r) {
        int n = tid + 256*r;
        inA[r] = *(const float2*)(xr + s0 + 2*n);
        int sb = s0 + HOP + 2*n;
        inB[r] = (sb < TT) ? *(const float2*)(xr + sb) : make_float2(0.f,0.f);
      }
    }
    stockham_pair<-1, true>(v, S4, tid);
    float* row0 = SPEC + (size_t)(bc*NFRM + f0)*RST;
    float* row1 = row0 + RST;
    #pragma unroll
    for (int j = 0; j < 5; ++j) {
      int k = tid + 256*j;
      if (k <= 1024) {
        float4 Zk = S4[PD4(k & 1023)];
        float4 Zm = S4[PD4((1024-k) & 1023)];
        float2 pk = *(const float2*)(PKt + 2*k);
        float zex = 0.5f*(Zk.x+Zm.x), zey = 0.5f*(Zk.y-Zm.y);
        float zox = 0.5f*(Zk.y+Zm.y), zoy = -0.5f*(Zk.x-Zm.x);
        float sax = zex + pk.x*zox - pk.y*zoy;
        float say = zey + pk.x*zoy + pk.y*zox;
        zex = 0.5f*(Zk.z+Zm.z); zey = 0.5f*(Zk.w-Zm.w);
        zox = 0.5f*(Zk.w+Zm.w); zoy = -0.5f*(Zk.z-Zm.z);
        float sbx = zex + pk.x*zox - pk.y*zoy;
        float sby = zey + pk.x*zoy + pk.y*zox;
        cr[j].x = (sax + cr[j].x)*Tv[j];
        cr[j].y = (say + cr[j].y)*Tv[j];
        *(float2*)(row0 + 2*k) = cr[j];
        cr[j].x = (sbx + cr[j].x)*Tv[j];
        cr[j].y = (sby + cr[j].y)*Tv[j];
        *(float2*)(row1 + 2*k) = cr[j];
      }
    }
    __syncthreads();
  }
  float* er = EB + (size_t)blk*RST;     // group-end local carry E_g
  #pragma unroll
  for (int j = 0; j < 5; ++j) {
    int k = tid + 256*j;
    if (k <= 1024) *(float2*)(er + 2*k) = cr[j];
  }
}

// ---------------- carry propagation across groups (in place: E -> carry-IN) -------------
__global__ void __launch_bounds__(256) k_carry(float* __restrict__ EB, const float* __restrict__ TM) {
  int gid = blockIdx.x*256 + threadIdx.x;
  if (gid >= NBC*KK) return;
  int bc = gid / KK, k = gid - bc*KK;
  int c = bc & (CC-1);
  float T = TM[c*KK + k];
  float t2 = T*T, t4 = t2*t2, t8 = t4*t4, T16 = t8*t8;
  float2 cc = make_float2(0.f, 0.f);
  for (int g = 0; g < GRP; ++g) {
    float* p = EB + (size_t)(bc*GRP + g)*RST + 2*k;
    float2 e = *(float2*)p;
    *(float2*)p = cc;                   // carry-in C_{g-1} for group g
    cc.x = e.x + T16*cc.x;              // C_g = E_g + T^16 C_{g-1}
    cc.y = e.y + T16*cc.y;
  }
}

// ---------------- fused decayed-carry + irfft + hann + OLA + tanh -> X ----------
// rowA of each round is software-prefetched during the previous round's FFT.
__global__ void __launch_bounds__(256) k_inv_ola(const float* __restrict__ SPEC,
    const float* __restrict__ EB, const float* __restrict__ TM,
    const float* __restrict__ HANN, const float* __restrict__ UPKt,
    const float* __restrict__ gains, float* __restrict__ X) {
  __shared__ float4 S4[1152];
  int tid = threadIdx.x;
  int blk = blockIdx.x;
  int g = blk & (GRP-1), bc = blk >> 3;
  int c = bc & (CC-1);
  int fb = g*FPG;
  float sg = gains[c];
  const float* ec = EB + (size_t)blk*RST;     // carry-in spectrum C_{g-1}
  float Tn[4], Tm[4]; float2 dN[4], dM[4];    // decayed carry (verified R9, absmax 0.031)
  #pragma unroll
  for (int r = 0; r < 4; ++r) {
    int n = tid + 256*r, m = 1024 - n;
    Tn[r] = TM[c*KK + n]; Tm[r] = TM[c*KK + m];
    dN[r] = *(const float2*)(ec + 2*n);
    dM[r] = *(const float2*)(ec + 2*m);
  }
  float2 pAn[4], pAm[4];                      // prefetched next-round rowA
  float2 pr0 = make_float2(0.f,0.f), pr1 = make_float2(0.f,0.f);
  float* xw = X + (size_t)bc*TT;
  const float sc = 1.0f/1024.0f;
  for (int rnd = 0; rnd <= FPG/2; ++rnd) {    // 9 rounds
    float4 v[4];
    #pragma unroll
    for (int r = 0; r < 4; ++r) {
      int n = tid + 256*r, m = 1024 - n;
      float2 An, Am, Bn, Bm;
      if (rnd == 0) { An = dN[r]; Am = dM[r]; }   // prev frame output = carry itself
      else {
        dN[r].x *= Tn[r]; dN[r].y *= Tn[r];
        dM[r].x *= Tm[r]; dM[r].y *= Tm[r];
        An = make_float2(pAn[r].x + dN[r].x, pAn[r].y + dN[r].y);
        Am = make_float2(pAm[r].x + dM[r].x, pAm[r].y + dM[r].y);
      }
      if (rnd < FPG/2) {
        const float* rowB = SPEC + (size_t)(bc*NFRM + fb + 2*rnd)*RST;
        float2 a  = *(const float2*)(rowB + 2*n);
        float2 bv = *(const float2*)(rowB + 2*m);
        dN[r].x *= Tn[r]; dN[r].y *= Tn[r];
        dM[r].x *= Tm[r]; dM[r].y *= Tm[r];
        Bn = make_float2(a.x + dN[r].x, a.y + dN[r].y);
        Bm = make_float2(bv.x + dM[r].x, bv.y + dM[r].y);
      } else { Bn = make_float2(0.f,0.f); Bm = make_float2(0.f,0.f); }
      float2 u = *(const float2*)(UPKt + 2*n);
      float zex = 0.5f*(An.x+Am.x), zey = 0.5f*(An.y-Am.y);
      float dx  = 0.5f*(An.x-Am.x), dy  = 0.5f*(An.y+Am.y);
      float zox = u.x*dx - u.y*dy, zoy = u.x*dy + u.y*dx;
      v[r].x = zex - zoy; v[r].y = zey + zox;
      zex = 0.5f*(Bn.x+Bm.x); zey = 0.5f*(Bn.y-Bm.y);
      dx  = 0.5f*(Bn.x-Bm.x); dy  = 0.5f*(Bn.y+Bm.y);
      zox = u.x*dx - u.y*dy; zoy = u.x*dy + u.y*dx;
      v[r].z = zex - zoy; v[r].w = zey + zox;
    }
    if (rnd < FPG/2) {                        // prefetch next round's rowA before FFT
      const float* rowA = SPEC + (size_t)(bc*NFRM + fb + 2*rnd + 1)*RST;
      #pragma unroll
      for (int r = 0; r < 4; ++r) {
        int n = tid + 256*r, m = 1024 - n;
        pAn[r] = *(const float2*)(rowA + 2*n);
        pAm[r] = *(const float2*)(rowA + 2*m);
      }
    }
    stockham_pair<1, false>(v, S4, tid);
    #pragma unroll
    for (int r = 0; r < 4; ++r) {             // hann + 1/1024 scale -> windowed frames
      int n = tid + 256*r;
      float2 h = *(const float2*)(HANN + 2*n);
      v[r].x *= sc*h.x; v[r].y *= sc*h.y;
      v[r].z *= sc*h.x; v[r].w *= sc*h.y;
    }
    if (rnd >= 1) {                           // emit frame fb+2rnd-1 (slot A)
      int tbase = (fb + 2*rnd - 1)*HOP;
      float2 o0 = make_float2(tanhf(sg*(v[0].x + pr0.x)), tanhf(sg*(v[0].y + pr0.y)));
      float2 o1 = make_float2(tanhf(sg*(v[1].x + pr1.x)), tanhf(sg*(v[1].y + pr1.y)));
      *(float2*)(xw + tbase + 2*tid)        = o0;
      *(float2*)(xw + tbase + 2*(tid+256))  = o1;
    }
    if (rnd < FPG/2) {                        // emit frame fb+2rnd (slot B)
      int tbase = (fb + 2*rnd)*HOP;
      float2 o0 = make_float2(tanhf(sg*(v[0].z + v[2].x)), tanhf(sg*(v[0].w + v[2].y)));
      float2 o1 = make_float2(tanhf(sg*(v[1].z + v[3].x)), tanhf(sg*(v[1].w + v[3].y)));
      *(float2*)(xw + tbase + 2*tid)        = o0;
      *(float2*)(xw + tbase + 2*(tid+256))  = o1;
      pr0 = make_float2(v[2].z, v[2].w);
      pr1 = make_float2(v[3].z, v[3].w);
    }
  }
}

// ---------------- out[b,t] += w_{l+1} * sum_c X[b,c,t]  (BW-bound; atomics regressed R9) --
__global__ void __launch_bounds__(256) k_out(const float* __restrict__ X,
    const float* __restrict__ mixer, int layer, float* __restrict__ out) {
  int gid = blockIdx.x*256 + threadIdx.x;
  int t4 = gid*4;
  int b = t4 >> 17, t = t4 & (TT-1);
  float m0=mixer[0],m1=mixer[1],m2=mixer[2],m3=mixer[3];
  float mx=fmaxf(fmaxf(m0,m1),fmaxf(m2,m3));
  float e[4]={__expf(m0-mx),__expf(m1-mx),__expf(m2-mx),__expf(m3-mx)};
  float w = e[layer+1]/(e[0]+e[1]+e[2]+e[3]);
  float4 acc = make_float4(0.f,0.f,0.f,0.f);
  #pragma unroll
  for (int c = 0; c < CC; ++c) {
    float4 xv = *(const float4*)(X + (size_t)(b*CC+c)*TT + t);
    acc.x += xv.x; acc.y += xv.y; acc.z += xv.z; acc.w += xv.w;
  }
  float4 o = *(float4*)(out + t4);
  o.x += w*acc.x; o.y += w*acc.y; o.z += w*acc.z; o.w += w*acc.w;
  *(float4*)(out + t4) = o;
}

extern "C" void kernel_launch(void* const* d_in, const int* in_sizes, int n_in,
                              void* d_out, int out_size, void* d_ws, size_t ws_size,
                              hipStream_t stream) {
  const float* sig        = (const float*)d_in[0];
  const float* noise      = (const float*)d_in[1];
  const float* decay      = (const float*)d_in[2];
  const float* mixer      = (const float*)d_in[3];
  const float* transfers  = (const float*)d_in[4];
  const float* mixer_mats = (const float*)d_in[5];
  const float* gains      = (const float*)d_in[6];
  const float* fb         = (const float*)d_in[7];
  float* out = (float*)d_out;
  float* ws  = (float*)d_ws;

  // ws floats: X 16.78M | SPEC 33.62M | EB 2.10M | TM 98K | tables | NZ* | FLG (~211 MB)
  float* X    = ws;
  float* SPEC = X + (size_t)16777216;
  float* EB   = SPEC + (size_t)NROWS*RST;
  float* TM   = EB + (size_t)NBC*GRP*RST;
  float* ENVt = TM + (size_t)NL*CC*KK;
  float* HANN = ENVt + CC*SPF;
  float* PKt  = HANN + 2048;
  float* UPKt = PKt + 2050;
  float* NZVf = UPKt + 2048;
  int*   NZI  = (int*)(NZVf + NL*CC*MAXNZ);
  int*   NZC  = NZI + NL*CC*MAXNZ;
  int*   FLG  = NZC + NL*CC;

  k_tables<<<64, 256, 0, stream>>>(decay, ENVt, HANN, PKt, UPKt);
  k_nnz<<<NL*CC, 64, 0, stream>>>(transfers, NZI, NZVf, NZC);
  k_tmat2<<<(NL*CC*KK + 255)/256, 256, 0, stream>>>(NZI, NZVf, NZC, fb, TM);
  k_ident<<<NL, 256, 0, stream>>>(mixer_mats, FLG);
  k_us_init<<<BB*TT/256, 256, 0, stream>>>(sig, noise, mixer, mixer_mats, ENVt, X, out);

  for (int l = 0; l < NL; ++l) {
    const float* TMl = TM + (size_t)l*CC*KK;
    if (l > 0)
      k_mix_cond<<<BB*TT/256, 256, 0, stream>>>(X, mixer_mats + (size_t)l*CC*CC, FLG, l);
    k_fwd_scan<<<NBC*GRP, 256, 0, stream>>>(X, SPEC, EB, TMl, HANN, PKt);
    k_carry<<<(NBC*KK + 255)/256, 256, 0, stream>>>(EB, TMl);
    k_inv_ola<<<NBC*GRP, 256, 0, stream>>>(SPEC, EB, TMl, HANN, UPKt, gains + (size_t)l*CC, X);
    k_out<<<BB*TT/1024, 256, 0, stream>>>(X, mixer, l, out);
  }
}

// Round 11
// 520.895 us; speedup vs baseline: 1.4887x; 1.0224x over previous
//
#include <hip/hip_runtime.h>
#include <math.h>

constexpr int BB   = 4;
constexpr int CC   = 32;
constexpr int TT   = 131072;
constexpr int NFRM = 128;
constexpr int KK   = 1025;
constexpr int HOP  = 1024;
constexpr int SPF  = 512;
constexpr int SIGF = 256;
constexpr int NL   = 3;
constexpr int RST  = 2052;
constexpr int NBC  = BB*CC;           // 128
constexpr int NROWS = NBC*NFRM;       // 16384
constexpr int MAXNZ = 256;
constexpr int GRP  = 8;               // groups per bc  (FPG=16 best: R7/R10=532us; FPG=8 regressed R8)
constexpr int FPG  = 16;              // frames per group

#define PD4(a) ((a) + ((a) >> 3))

__device__ __forceinline__ float4 f4add(float4 a, float4 b){return make_float4(a.x+b.x,a.y+b.y,a.z+b.z,a.w+b.w);}
__device__ __forceinline__ float4 f4sub(float4 a, float4 b){return make_float4(a.x-b.x,a.y-b.y,a.z-b.z,a.w-b.w);}
__device__ __forceinline__ float4 cmul4(float4 v, float c, float s){
  return make_float4(v.x*c - v.y*s, v.x*s + v.y*c, v.z*c - v.w*s, v.z*s + v.w*c);
}

template<int SGN>
__device__ __forceinline__ void dft4p(float4 v[4]) {
  float4 b0=f4add(v[0],v[2]), b1=f4sub(v[0],v[2]), b2=f4add(v[1],v[3]), b3=f4sub(v[1],v[3]);
  float4 ib3 = (SGN<0)? make_float4(b3.y,-b3.x,b3.w,-b3.z) : make_float4(-b3.y,b3.x,-b3.w,b3.z);
  v[0]=f4add(b0,b2); v[2]=f4sub(b0,b2);
  v[1]=f4add(b1,ib3); v[3]=f4sub(b1,ib3);
}

// Stockham radix-4 FFT-1024, 256 threads, two interleaved FFTs (.xy/.zw halves).
// PING-PONG LDS: each exchange stage stores to the alternate buffer -> no WAR hazard,
// 1 __syncthreads per stage instead of 2. Final store (FINAL_STORE) lands in S4a
// (stores at Ns=1,4,16,64,256 use buffers 0,1,0,1,0).
template<int SGN, bool FINAL_STORE>
__device__ __forceinline__ void stockham_pair(float4 v[4], float4* S4a, float4* S4b, int tid) {
  int pb = 0;
  #pragma unroll
  for (int Ns=1; Ns<1024; Ns*=4) {
    if (Ns>1) {
      int k = tid & (Ns-1);
      float ang = (float)SGN * 6.28318530717958647692f * (float)k / (float)(4*Ns);
      float s1,c1; __sincosf(ang,&s1,&c1);
      float c2=c1*c1-s1*s1, s2=2.f*c1*s1;
      float c3=c2*c1-s2*s1, s3=c2*s1+s2*c1;
      v[1]=cmul4(v[1],c1,s1); v[2]=cmul4(v[2],c2,s2); v[3]=cmul4(v[3],c3,s3);
    }
    dft4p<SGN>(v);
    if (Ns<256 || FINAL_STORE) {
      float4* B = (pb == 0) ? S4a : S4b;
      pb ^= 1;
      int idxD = ((tid & ~(Ns-1))<<2) | (tid & (Ns-1));
      B[PD4(idxD       )] = v[0];
      B[PD4(idxD +   Ns)] = v[1];
      B[PD4(idxD + 2*Ns)] = v[2];
      B[PD4(idxD + 3*Ns)] = v[3];
      __syncthreads();
      if (Ns<256) {
        v[0]=B[PD4(tid)]; v[1]=B[PD4(tid+256)]; v[2]=B[PD4(tid+512)]; v[3]=B[PD4(tid+768)];
        // no trailing sync: next stage stores to the OTHER buffer
      }
    }
  }
}

// ---------------- tables ----------------
__global__ void k_tables(const float* __restrict__ decay, float* __restrict__ ENVt,
                         float* __restrict__ HANN, float* __restrict__ PKt,
                         float* __restrict__ UPKt) {
  int gid = blockIdx.x*256 + threadIdx.x;
  if (gid < CC*SPF) {
    int c = gid >> 9, r = gid & 511;
    float d = decay[c];
    float env;
    if (r == 511) env = (d == 0.f) ? 1.f : 0.f;
    else          env = powf((float)(511-r)*(1.0f/511.0f), d);
    ENVt[gid] = env;
  }
  if (gid < 2048) HANN[gid] = 0.5f - 0.5f*cosf((float)gid*(float)(M_PI/1024.0));
  if (gid <= 1024) { float s,c; sincosf(-(float)M_PI*(float)gid*(1.0f/1024.0f),&s,&c); PKt[2*gid]=c; PKt[2*gid+1]=s; }
  if (gid <  1024) { float s,c; sincosf( (float)M_PI*(float)gid*(1.0f/1024.0f),&s,&c); UPKt[2*gid]=c; UPKt[2*gid+1]=s; }
}

// ---------------- sparse transfers: compact then expand ----------------
__global__ void __launch_bounds__(64) k_nnz(const float* __restrict__ tr,
    int* __restrict__ NZI, float* __restrict__ NZV, int* __restrict__ NZC) {
  int lc = blockIdx.x;
  int lane = threadIdx.x;
  const float* trow = tr + (size_t)lc*KK;
  int base = 0;
  for (int start = 0; start < KK; start += 64) {
    int kp = start + lane;
    float v = (kp < KK) ? trow[kp] : 0.f;
    unsigned long long m = __ballot(v != 0.f);
    int pos = base + __popcll(m & ((1ull<<lane)-1ull));
    if (v != 0.f && pos < MAXNZ) { NZI[lc*MAXNZ+pos] = kp; NZV[lc*MAXNZ+pos] = v; }
    base += __popcll(m);
  }
  if (lane == 0) NZC[lc] = (base < MAXNZ) ? base : MAXNZ;
}

__global__ void __launch_bounds__(256) k_tmat2(const int* __restrict__ NZI,
    const float* __restrict__ NZV, const int* __restrict__ NZC,
    const float* __restrict__ fb, float* __restrict__ TM) {
  int gid = blockIdx.x*256 + threadIdx.x;
  if (gid >= NL*CC*KK) return;
  int k = gid % KK, lc = gid / KK;
  int n = NZC[lc];
  const int*   zi = NZI + lc*MAXNZ;
  const float* zv = NZV + lc*MAXNZ;
  float acc = 0.f;
  for (int i = 0; i < n; ++i)
    acc = fmaf(zv[i], fb[(size_t)zi[i]*KK + k], acc);
  TM[gid] = acc;
}

// ---------------- per-layer identity check on mixer matrices ----------------
__global__ void k_ident(const float* __restrict__ mats, int* __restrict__ FLG) {
  int l = blockIdx.x;
  const float* M = mats + (size_t)l*CC*CC;
  __shared__ int ok;
  if (threadIdx.x == 0) ok = 1;
  __syncthreads();
  for (int i = threadIdx.x; i < CC*CC; i += 256) {
    float ex = ((i>>5) == (i&31)) ? 1.f : 0.f;
    if (M[i] != ex) ok = 0;
  }
  __syncthreads();
  if (threadIdx.x == 0) FLG[l] = ok;
}

// ---------------- fused upsample+envelope+noise + layer-0 mix + out init + sig copy ------
__global__ void __launch_bounds__(256) k_us_init(const float* __restrict__ sig,
    const float* __restrict__ noise, const float* __restrict__ mixer,
    const float* __restrict__ M0, const float* __restrict__ ENVt,
    float* __restrict__ X, float* __restrict__ out) {
  __shared__ float sM[CC*CC];
  int tid = threadIdx.x;
  for (int i = tid; i < CC*CC; i += 256) sM[i] = M0[i];
  __syncthreads();
  int gid = blockIdx.x*256 + tid;
  int b = gid >> 17, t = gid & (TT-1);
  int q = t >> 9, r = t & 511;
  float nz = noise[t];
  float u[CC]; float s = 0.f;
  #pragma unroll
  for (int c = 0; c < CC; ++c) { u[c] = sig[(b*CC+c)*SIGF + q] * ENVt[c*SPF + r]; s += u[c]; }
  float m0=mixer[0],m1=mixer[1],m2=mixer[2],m3=mixer[3];
  float mx=fmaxf(fmaxf(m0,m1),fmaxf(m2,m3));
  float e0=__expf(m0-mx),e1=__expf(m1-mx),e2=__expf(m2-mx),e3=__expf(m3-mx);
  float w0=e0/(e0+e1+e2+e3);
  out[gid] = w0 * nz * s;
  #pragma unroll
  for (int d = 0; d < CC; ++d) {
    float acc = 0.f;
    #pragma unroll
    for (int c = 0; c < CC; ++c) acc = fmaf(u[c], sM[c*CC+d], acc);
    X[(size_t)(b*CC+d)*TT + t] = nz * acc;
  }
  if (gid < BB*CC*SIGF) out[BB*TT + gid] = sig[gid];
}

// ---------------- conditional in-place channel mix (no-op when identity) -----------------
__global__ void __launch_bounds__(256) k_mix_cond(float* __restrict__ X,
    const float* __restrict__ M, const int* __restrict__ FLG, int layer) {
  if (FLG[layer]) return;
  __shared__ float sM[CC*CC];
  int tid = threadIdx.x;
  for (int i = tid; i < CC*CC; i += 256) sM[i] = M[i];
  __syncthreads();
  int gid = blockIdx.x*256 + tid;
  int b = gid >> 17, t = gid & (TT-1);
  float* xp = X + (size_t)b*CC*TT + t;
  float xv[CC];
  #pragma unroll
  for (int c = 0; c < CC; ++c) xv[c] = xp[(size_t)c*TT];
  for (int d = 0; d < CC; ++d) {
    float acc = 0.f;
    #pragma unroll
    for (int c = 0; c < CC; ++c) acc = fmaf(xv[c], sM[c*CC+d], acc);
    xp[(size_t)d*TT] = acc;
  }
}

// ---------------- fused forward FFT + chunk-local scan, input software-pipelined --------
__global__ void __launch_bounds__(256) k_fwd_scan(const float* __restrict__ X,
    float* __restrict__ SPEC, float* __restrict__ EB, const float* __restrict__ TM,
    const float* __restrict__ HANN, const float* __restrict__ PKt) {
  __shared__ float4 S4a[1152];
  __shared__ float4 S4b[1152];
  int tid = threadIdx.x;
  int blk = blockIdx.x;                 // bc*GRP + g
  int g = blk & (GRP-1), bc = blk >> 3;
  int c = bc & (CC-1);
  const float* xr = X + (size_t)bc*TT;
  float Tv[5]; float2 cr[5];
  #pragma unroll
  for (int j = 0; j < 5; ++j) {
    int k = tid + 256*j;
    Tv[j] = (k <= 1024) ? TM[c*KK + k] : 0.f;
    cr[j] = make_float2(0.f, 0.f);
  }
  // preload pair 0 input
  float2 inA[4], inB[4];
  {
    int s0 = g*FPG*HOP;
    #pragma unroll
    for (int r = 0; r < 4; ++r) {
      int n = tid + 256*r;
      inA[r] = *(const float2*)(xr + s0 + 2*n);
      int sb = s0 + HOP + 2*n;
      inB[r] = (sb < TT) ? *(const float2*)(xr + sb) : make_float2(0.f,0.f);
    }
  }
  for (int p = 0; p < FPG/2; ++p) {
    int f0 = g*FPG + 2*p;
    float4 v[4];
    #pragma unroll
    for (int r = 0; r < 4; ++r) {
      int n = tid + 256*r;
      float2 h = *(const float2*)(HANN + 2*n);
      v[r] = make_float4(inA[r].x*h.x, inA[r].y*h.y, inB[r].x*h.x, inB[r].y*h.y);
    }
    if (p < FPG/2 - 1) {                // prefetch pair p+1 input before FFT (latency hidden)
      int s0 = (f0 + 2)*HOP;
      #pragma unroll
      for (int r = 0; r < 4; ++r) {
        int n = tid + 256*r;
        inA[r] = *(const float2*)(xr + s0 + 2*n);
        int sb = s0 + HOP + 2*n;
        inB[r] = (sb < TT) ? *(const float2*)(xr + sb) : make_float2(0.f,0.f);
      }
    }
    stockham_pair<-1, true>(v, S4a, S4b, tid);   // result in S4a
    float* row0 = SPEC + (size_t)(bc*NFRM + f0)*RST;
    float* row1 = row0 + RST;
    #pragma unroll
    for (int j = 0; j < 5; ++j) {
      int k = tid + 256*j;
      if (k <= 1024) {
        float4 Zk = S4a[PD4(k & 1023)];
        float4 Zm = S4a[PD4((1024-k) & 1023)];
        float2 pk = *(const float2*)(PKt + 2*k);
        float zex = 0.5f*(Zk.x+Zm.x), zey = 0.5f*(Zk.y-Zm.y);
        float zox = 0.5f*(Zk.y+Zm.y), zoy = -0.5f*(Zk.x-Zm.x);
        float sax = zex + pk.x*zox - pk.y*zoy;
        float say = zey + pk.x*zoy + pk.y*zox;
        zex = 0.5f*(Zk.z+Zm.z); zey = 0.5f*(Zk.w-Zm.w);
        zox = 0.5f*(Zk.w+Zm.w); zoy = -0.5f*(Zk.z-Zm.z);
        float sbx = zex + pk.x*zox - pk.y*zoy;
        float sby = zey + pk.x*zoy + pk.y*zox;
        cr[j].x = (sax + cr[j].x)*Tv[j];
        cr[j].y = (say + cr[j].y)*Tv[j];
        *(float2*)(row0 + 2*k) = cr[j];
        cr[j].x = (sbx + cr[j].x)*Tv[j];
        cr[j].y = (sby + cr[j].y)*Tv[j];
        *(float2*)(row1 + 2*k) = cr[j];
      }
    }
    __syncthreads();                    // protect S4a (pack reads) before next round's store
  }
  float* er = EB + (size_t)blk*RST;     // group-end local carry E_g
  #pragma unroll
  for (int j = 0; j < 5; ++j) {
    int k = tid + 256*j;
    if (k <= 1024) *(float2*)(er + 2*k) = cr[j];
  }
}

// ---------------- carry propagation across groups (in place: E -> carry-IN) -------------
__global__ void __launch_bounds__(256) k_carry(float* __restrict__ EB, const float* __restrict__ TM) {
  int gid = blockIdx.x*256 + threadIdx.x;
  if (gid >= NBC*KK) return;
  int bc = gid / KK, k = gid - bc*KK;
  int c = bc & (CC-1);
  float T = TM[c*KK + k];
  float t2 = T*T, t4 = t2*t2, t8 = t4*t4, T16 = t8*t8;
  float2 cc = make_float2(0.f, 0.f);
  for (int g = 0; g < GRP; ++g) {
    float* p = EB + (size_t)(bc*GRP + g)*RST + 2*k;
    float2 e = *(float2*)p;
    *(float2*)p = cc;                   // carry-in C_{g-1} for group g
    cc.x = e.x + T16*cc.x;              // C_g = E_g + T^16 C_{g-1}
    cc.y = e.y + T16*cc.y;
  }
}

// ---------------- fused decayed-carry + irfft + hann + OLA + tanh -> X ----------
__global__ void __launch_bounds__(256) k_inv_ola(const float* __restrict__ SPEC,
    const float* __restrict__ EB, const float* __restrict__ TM,
    const float* __restrict__ HANN, const float* __restrict__ UPKt,
    const float* __restrict__ gains, float* __restrict__ X) {
  __shared__ float4 S4a[1152];
  __shared__ float4 S4b[1152];
  int tid = threadIdx.x;
  int blk = blockIdx.x;
  int g = blk & (GRP-1), bc = blk >> 3;
  int c = bc & (CC-1);
  int fb = g*FPG;
  float sg = gains[c];
  const float* ec = EB + (size_t)blk*RST;     // carry-in spectrum C_{g-1}
  float Tn[4], Tm[4]; float2 dN[4], dM[4];    // decayed carry
  #pragma unroll
  for (int r = 0; r < 4; ++r) {
    int n = tid + 256*r, m = 1024 - n;
    Tn[r] = TM[c*KK + n]; Tm[r] = TM[c*KK + m];
    dN[r] = *(const float2*)(ec + 2*n);
    dM[r] = *(const float2*)(ec + 2*m);
  }
  float2 pAn[4], pAm[4];                      // prefetched next-round rowA
  float2 pr0 = make_float2(0.f,0.f), pr1 = make_float2(0.f,0.f);
  float* xw = X + (size_t)bc*TT;
  const float sc = 1.0f/1024.0f;
  for (int rnd = 0; rnd <= FPG/2; ++rnd) {    // 9 rounds
    float4 v[4];
    #pragma unroll
    for (int r = 0; r < 4; ++r) {
      int n = tid + 256*r, m = 1024 - n;
      float2 An, Am, Bn, Bm;
      if (rnd == 0) { An = dN[r]; Am = dM[r]; }   // prev frame output = carry itself
      else {
        dN[r].x *= Tn[r]; dN[r].y *= Tn[r];
        dM[r].x *= Tm[r]; dM[r].y *= Tm[r];
        An = make_float2(pAn[r].x + dN[r].x, pAn[r].y + dN[r].y);
        Am = make_float2(pAm[r].x + dM[r].x, pAm[r].y + dM[r].y);
      }
      if (rnd < FPG/2) {
        const float* rowB = SPEC + (size_t)(bc*NFRM + fb + 2*rnd)*RST;
        float2 a  = *(const float2*)(rowB + 2*n);
        float2 bv = *(const float2*)(rowB + 2*m);
        dN[r].x *= Tn[r]; dN[r].y *= Tn[r];
        dM[r].x *= Tm[r]; dM[r].y *= Tm[r];
        Bn = make_float2(a.x + dN[r].x, a.y + dN[r].y);
        Bm = make_float2(bv.x + dM[r].x, bv.y + dM[r].y);
      } else { Bn = make_float2(0.f,0.f); Bm = make_float2(0.f,0.f); }
      float2 u = *(const float2*)(UPKt + 2*n);
      float zex = 0.5f*(An.x+Am.x), zey = 0.5f*(An.y-Am.y);
      float dx  = 0.5f*(An.x-Am.x), dy  = 0.5f*(An.y+Am.y);
      float zox = u.x*dx - u.y*dy, zoy = u.x*dy + u.y*dx;
      v[r].x = zex - zoy; v[r].y = zey + zox;
      zex = 0.5f*(Bn.x+Bm.x); zey = 0.5f*(Bn.y-Bm.y);
      dx  = 0.5f*(Bn.x-Bm.x); dy  = 0.5f*(Bn.y+Bm.y);
      zox = u.x*dx - u.y*dy; zoy = u.x*dy + u.y*dx;
      v[r].z = zex - zoy; v[r].w = zey + zox;
    }
    if (rnd < FPG/2) {                        // prefetch next round's rowA before FFT
      const float* rowA = SPEC + (size_t)(bc*NFRM + fb + 2*rnd + 1)*RST;
      #pragma unroll
      for (int r = 0; r < 4; ++r) {
        int n = tid + 256*r, m = 1024 - n;
        pAn[r] = *(const float2*)(rowA + 2*n);
        pAm[r] = *(const float2*)(rowA + 2*m);
      }
    }
    stockham_pair<1, false>(v, S4a, S4b, tid);
    #pragma unroll
    for (int r = 0; r < 4; ++r) {             // hann + 1/1024 scale -> windowed frames
      int n = tid + 256*r;
      float2 h = *(const float2*)(HANN + 2*n);
      v[r].x *= sc*h.x; v[r].y *= sc*h.y;
      v[r].z *= sc*h.x; v[r].w *= sc*h.y;
    }
    if (rnd >= 1) {                           // emit frame fb+2rnd-1 (slot A)
      int tbase = (fb + 2*rnd - 1)*HOP;
      float2 o0 = make_float2(tanhf(sg*(v[0].x + pr0.x)), tanhf(sg*(v[0].y + pr0.y)));
      float2 o1 = make_float2(tanhf(sg*(v[1].x + pr1.x)), tanhf(sg*(v[1].y + pr1.y)));
      *(float2*)(xw + tbase + 2*tid)        = o0;
      *(float2*)(xw + tbase + 2*(tid+256))  = o1;
    }
    if (rnd < FPG/2) {                        // emit frame fb+2rnd (slot B)
      int tbase = (fb + 2*rnd)*HOP;
      float2 o0 = make_float2(tanhf(sg*(v[0].z + v[2].x)), tanhf(sg*(v[0].w + v[2].y)));
      float2 o1 = make_float2(tanhf(sg*(v[1].z + v[3].x)), tanhf(sg*(v[1].w + v[3].y)));
      *(float2*)(xw + tbase + 2*tid)        = o0;
      *(float2*)(xw + tbase + 2*(tid+256))  = o1;
      pr0 = make_float2(v[2].z, v[2].w);
      pr1 = make_float2(v[3].z, v[3].w);
    }
  }
}

// ---------------- out[b,t] += w_{l+1} * sum_c X[b,c,t]  (streaming; atomics regressed R9) --
__global__ void __launch_bounds__(256) k_out(const float* __restrict__ X,
    const float* __restrict__ mixer, int layer, float* __restrict__ out) {
  int gid = blockIdx.x*256 + threadIdx.x;
  int t4 = gid*4;
  int b = t4 >> 17, t = t4 & (TT-1);
  float m0=mixer[0],m1=mixer[1],m2=mixer[2],m3=mixer[3];
  float mx=fmaxf(fmaxf(m0,m1),fmaxf(m2,m3));
  float e[4]={__expf(m0-mx),__expf(m1-mx),__expf(m2-mx),__expf(m3-mx)};
  float w = e[layer+1]/(e[0]+e[1]+e[2]+e[3]);
  float4 acc = make_float4(0.f,0.f,0.f,0.f);
  #pragma unroll
  for (int c = 0; c < CC; ++c) {
    float4 xv = *(const float4*)(X + (size_t)(b*CC+c)*TT + t);
    acc.x += xv.x; acc.y += xv.y; acc.z += xv.z; acc.w += xv.w;
  }
  float4 o = *(float4*)(out + t4);
  o.x += w*acc.x; o.y += w*acc.y; o.z += w*acc.z; o.w += w*acc.w;
  *(float4*)(out + t4) = o;
}

extern "C" void kernel_launch(void* const* d_in, const int* in_sizes, int n_in,
                              void* d_out, int out_size, void* d_ws, size_t ws_size,
                              hipStream_t stream) {
  const float* sig        = (const float*)d_in[0];
  const float* noise      = (const float*)d_in[1];
  const float* decay      = (const float*)d_in[2];
  const float* mixer      = (const float*)d_in[3];
  const float* transfers  = (const float*)d_in[4];
  const float* mixer_mats = (const float*)d_in[5];
  const float* gains      = (const float*)d_in[6];
  const float* fb         = (const float*)d_in[7];
  float* out = (float*)d_out;
  float* ws  = (float*)d_ws;

  // ws floats: X 16.78M | SPEC 33.62M | EB 2.10M | TM 98K | tables | NZ* | FLG (~211 MB)
  float* X    = ws;
  float* SPEC = X + (size_t)16777216;
  float* EB   = SPEC + (size_t)NROWS*RST;
  float* TM   = EB + (size_t)NBC*GRP*RST;
  float* ENVt = TM + (size_t)NL*CC*KK;
  float* HANN = ENVt + CC*SPF;
  float* PKt  = HANN + 2048;
  float* UPKt = PKt + 2050;
  float* NZVf = UPKt + 2048;
  int*   NZI  = (int*)(NZVf + NL*CC*MAXNZ);
  int*   NZC  = NZI + NL*CC*MAXNZ;
  int*   FLG  = NZC + NL*CC;

  k_tables<<<64, 256, 0, stream>>>(decay, ENVt, HANN, PKt, UPKt);
  k_nnz<<<NL*CC, 64, 0, stream>>>(transfers, NZI, NZVf, NZC);
  k_tmat2<<<(NL*CC*KK + 255)/256, 256, 0, stream>>>(NZI, NZVf, NZC, fb, TM);
  k_ident<<<NL, 256, 0, stream>>>(mixer_mats, FLG);
  k_us_init<<<BB*TT/256, 256, 0, stream>>>(sig, noise, mixer, mixer_mats, ENVt, X, out);

  for (int l = 0; l < NL; ++l) {
    const float* TMl = TM + (size_t)l*CC*KK;
    if (l > 0)
      k_mix_cond<<<BB*TT/256, 256, 0, stream>>>(X, mixer_mats + (size_t)l*CC*CC, FLG, l);
    k_fwd_scan<<<NBC*GRP, 256, 0, stream>>>(X, SPEC, EB, TMl, HANN, PKt);
    k_carry<<<(NBC*KK + 255)/256, 256, 0, stream>>>(EB, TMl);
    k_inv_ola<<<NBC*GRP, 256, 0, stream>>>(SPEC, EB, TMl, HANN, UPKt, gains + (size_t)l*CC, X);
    k_out<<<BB*TT/1024, 256, 0, stream>>>(X, mixer, l, out);
  }
}